// Round 1
// 1177.668 us; speedup vs baseline: 1.2763x; 1.2763x over previous
//
#include <hip/hip_runtime.h>

typedef __attribute__((ext_vector_type(8))) short short8;   // 8 bf16 (MFMA A/B frag)
typedef __attribute__((ext_vector_type(4))) float f32x4;    // MFMA C/D frag
typedef __attribute__((ext_vector_type(2))) unsigned int u32x2;
typedef __attribute__((ext_vector_type(4))) unsigned int u32x4;

// ---------------- new (big-ws) layout, ~302 MiB ----------------
#define WS_ET   0u            // bf16 Et [256][16384]      8388608
#define WS_P2   8388608u      // f32 P2 [8][4096][256]    33554432
#define WS_ST   41943040u     // f32 St [4096][256]        4194304
#define WS_SB   46137344u     // bf16 Sb [256][4096]       2097152
#define WS_CS   48234496u     // f32 cs [50][256]            51200
#define WS_UG   48285696u     // f32 uG [64]                   256
#define WS_CNT  48285952u     // int cnt [50][64]   (k0 zeroes 25600B; spill into WB head is rewritten by k0w)
#define WS_WB   48298752u     // bf16 Wb  [16384][4096]  134217728
#define WS_WBT  182516480u    // bf16 WbT [4096][16384]  134217728
#define WS_END  316734208u

// ---------------- old (small-ws) fallback layout, ~30 MiB ----------------
#define WO_ET  0u
#define WO_P2  8388608u
#define WO_ST  25165824u
#define WO_SB  29360128u
#define WO_CS  31457280u
#define WO_UG  31508480u
#define WO_CNT 31508736u
#define WO_END 31534336u

static __device__ __forceinline__ unsigned short f2bf(float x) {
  union { float f; unsigned u; } v; v.f = x;
  unsigned r = v.u + 0x7FFFu + ((v.u >> 16) & 1u);   // RNE
  return (unsigned short)(r >> 16);
}

static __device__ __forceinline__ void gl_lds16(const void* g, void* l) {
  __builtin_amdgcn_global_load_lds(
      (const __attribute__((address_space(1))) void*)g,
      (__attribute__((address_space(3))) void*)l, 16, 0, 0);
}

// uG[s] = -1 + sum(||delta||^2); converged step <=> value <= -1 + 1e-6.
static __device__ __forceinline__ bool conv_before(const float* uG, int s) {
  bool d = false;
  for (int i = 0; i < s; ++i) d |= (uG[i] <= (-1.0f + 1.0e-6f));
  return d;
}

__global__ void sentinel_kernel(float* out, float v) { out[0] = v; }

// ================= K0: setup (shared by both paths) =================
__global__ void __launch_bounds__(256)
k0_setup(const float* __restrict__ inp, float* __restrict__ St,
         unsigned short* __restrict__ Sb, float* __restrict__ csG,
         float* __restrict__ uG, int* __restrict__ cnt)
{
  const int t = threadIdx.x, blk = blockIdx.x;
  if (blk == 0) {
    for (int i = t; i < 50 * 256; i += 256) csG[i] = 0.0f;
    if (t < 64) uG[t] = -1.0f;
  } else if (blk == 1) {
    for (int i = t; i < 50 * 128; i += 256) cnt[i] = 0;
  }
  #pragma unroll
  for (int i = 0; i < 8; ++i) {
    int idx = blk * 2048 + i * 256 + t;        // flat b*4096+n, covers 1M
    float v = inp[idx];
    Sb[idx] = f2bf(v);
    St[(idx & 4095) * 256 + (idx >> 12)] = v;
  }
}

// ================= K0W: W fp32 -> Wb bf16 [m][n] and WbT bf16 [n][m] (once) =================
__global__ void __launch_bounds__(256)
k0w_conv(const float* __restrict__ Wg, unsigned short* __restrict__ Wb,
         unsigned short* __restrict__ WbT)
{
  __shared__ unsigned short Tl[64][66];        // pad 66: conflict-free col reads
  const int t = threadIdx.x;
  const int r = t >> 2, q = t & 3;
  for (int i = 0; i < 4; ++i) {
    const int ti = blockIdx.x * 4 + i;         // 16384 tiles of 64x64
    const int m0 = (ti >> 6) * 64;
    const int n0 = (ti & 63) * 64;
    const float* src = Wg + (size_t)(m0 + r) * 4096 + n0 + q * 16;
    unsigned short h[16] __attribute__((aligned(16)));
    #pragma unroll
    for (int v = 0; v < 4; ++v) {
      float4 f = *(const float4*)(src + v * 4);
      h[v*4+0] = f2bf(f.x); h[v*4+1] = f2bf(f.y);
      h[v*4+2] = f2bf(f.z); h[v*4+3] = f2bf(f.w);
    }
    unsigned short* wbp = Wb + (size_t)(m0 + r) * 4096 + n0 + q * 16;
    *(u32x4*)wbp       = *(const u32x4*)h;
    *(u32x4*)(wbp + 8) = *(const u32x4*)(h + 8);
    if (i) __syncthreads();
    #pragma unroll
    for (int k = 0; k < 16; ++k) Tl[r][q * 16 + k] = h[k];
    __syncthreads();
    unsigned short g[16] __attribute__((aligned(16)));
    const int nn = t >> 2;
    #pragma unroll
    for (int k = 0; k < 16; ++k) g[k] = Tl[q * 16 + k][nn];
    unsigned short* wtp = WbT + (size_t)(n0 + nn) * 16384 + m0 + q * 16;
    *(u32x4*)wtp       = *(const u32x4*)g;
    *(u32x4*)(wtp + 8) = *(const u32x4*)(g + 8);
  }
}

// ================= shared 128x128 bt-GEMM core, BK=64, gl_lds both operands =================
// LDS rows are 64 bf16 = 128B -> 16B-slot XOR-swizzle (slot ^= row&7), applied by
// pre-swizzling the per-lane GLOBAL source (gl_lds dest must stay linear, m104/m173).
template<int ITERS>
static __device__ __forceinline__ void gemm_core(
    const unsigned short* __restrict__ Ag, const size_t lda, const int arow0,
    const unsigned short* __restrict__ Bg, const size_t ldb, const int brow0,
    const int kbase, unsigned short* smem, f32x4 (&acc)[4][4], const int t)
{
  const int lane = t & 63, wv = t >> 6;
  const int l15 = lane & 15, quad = lane >> 4;
  const int wr = wv >> 1, wc = wv & 1;
  const int xr = l15 & 7;
  unsigned short* As0 = smem;                  // [128][64] bf16, 16KB each
  unsigned short* As1 = smem + 8192;
  unsigned short* Bs0 = smem + 16384;
  unsigned short* Bs1 = smem + 24576;
  const int srow = wv * 8 + (lane >> 3);                 // staging row in 32-row group
  const int ks   = ((lane & 7) ^ (lane >> 3)) * 8;       // pre-swizzled k-slot (shorts)
  const unsigned short* gA = Ag + (size_t)(arow0 + srow) * lda + kbase + ks;
  const unsigned short* gB = Bg + (size_t)(brow0 + srow) * ldb + kbase + ks;
  const int sb = wv * 512;                               // LDS short-offset of wave's 8 rows

#define STAGE(itv, Ad, Bd)                                                        \
  { _Pragma("unroll") for (int j_ = 0; j_ < 4; ++j_) {                            \
      gl_lds16(gA + (size_t)j_ * 32 * lda + (size_t)(itv) * 64, (Ad) + j_ * 2048 + sb); \
      gl_lds16(gB + (size_t)j_ * 32 * ldb + (size_t)(itv) * 64, (Bd) + j_ * 2048 + sb); } }

  STAGE(0, As0, Bs0);
  __syncthreads();
  #pragma unroll 2
  for (int it = 0; it < ITERS; ++it) {
    unsigned short *Asc, *Bsc, *Asn, *Bsn;
    if (it & 1) { Asc = As1; Bsc = Bs1; Asn = As0; Bsn = Bs0; }
    else        { Asc = As0; Bsc = Bs0; Asn = As1; Bsn = Bs1; }
    if (it + 1 < ITERS) STAGE(it + 1, Asn, Bsn);   // issue BEFORE compute: latency hides under MFMA
    #pragma unroll
    for (int kk = 0; kk < 2; ++kk) {
      short8 af[4], bq[4];
      const int so = ((kk * 4 + quad) ^ xr) << 3;  // swizzled read slot
      #pragma unroll
      for (int r = 0; r < 4; ++r)
        af[r] = *(const short8*)(Asc + (wr * 64 + r * 16 + l15) * 64 + so);
      #pragma unroll
      for (int c = 0; c < 4; ++c)
        bq[c] = *(const short8*)(Bsc + (wc * 64 + c * 16 + l15) * 64 + so);
      #pragma unroll
      for (int r = 0; r < 4; ++r)
        #pragma unroll
        for (int c = 0; c < 4; ++c)
          acc[r][c] = __builtin_amdgcn_mfma_f32_16x16x32_bf16(af[r], bq[c], acc[r][c], 0, 0, 0);
    }
    __syncthreads();
  }
#undef STAGE
}

// ================= K1 (new): h = W @ v, fused exp -> Et, colsum =================
__global__ void __launch_bounds__(256, 2)
k1_gemm1(const unsigned short* __restrict__ Wb, const float* __restrict__ betap,
         const unsigned short* __restrict__ Sb, unsigned short* __restrict__ Et,
         float* __restrict__ csG, const float* __restrict__ uG, int s)
{
  if (conv_before(uG, s)) return;
  __shared__ __align__(16) unsigned char smem_[65536];
  const int t = threadIdx.x;
  const int w = ((blockIdx.x & 7) << 5) | (blockIdx.x >> 3);  // XCD-chunked (256 = 8*32)
  const int mt = w >> 1, bt = w & 1;
  const int m0 = mt * 128, b0 = bt * 128;

  f32x4 acc[4][4];
  #pragma unroll
  for (int r = 0; r < 4; ++r)
    #pragma unroll
    for (int c = 0; c < 4; ++c) { f32x4 z = {0.f,0.f,0.f,0.f}; acc[r][c] = z; }

  gemm_core<64>(Wb, 4096, m0, Sb, 4096, b0, 0, (unsigned short*)smem_, acc, t);

  // epilogue: e = exp(beta*h) -> Et bf16 [b][m]; per-column sums -> csG
  const float beta = betap[0];
  const int lane = t & 63, wv = t >> 6, l15 = lane & 15, quad = lane >> 4;
  const int wr = wv >> 1, wc = wv & 1;
  #pragma unroll
  for (int c = 0; c < 4; ++c) {
    const int b = b0 + wc * 64 + c * 16 + l15;
    float cs = 0.0f;
    #pragma unroll
    for (int r = 0; r < 4; ++r) {
      unsigned short eb[4] __attribute__((aligned(8)));
      #pragma unroll
      for (int j = 0; j < 4; ++j) {
        float e = __expf(beta * acc[r][c][j]);   // D row(m)=quad*4+j, col(b)=l15
        cs += e;
        eb[j] = f2bf(e);
      }
      *(u32x2*)(Et + (size_t)b * 16384 + m0 + wr * 64 + r * 16 + quad * 4) = *(const u32x2*)eb;
    }
    cs += __shfl_xor(cs, 16, 64);
    cs += __shfl_xor(cs, 32, 64);
    if (quad == 0) atomicAdd(&csG[s * 256 + b], cs);
  }
}

// ================= K2 (new): P2[kc] = partial(W^T @ e); 8-way split-K; last arriver combines =================
__global__ void __launch_bounds__(256, 2)
k2_gemm2(const unsigned short* __restrict__ WbT, const float* __restrict__ taup,
         const unsigned short* __restrict__ Et, float* __restrict__ P2,
         float* __restrict__ St, unsigned short* __restrict__ Sb,
         const float* __restrict__ csG, float* __restrict__ uG,
         int* __restrict__ cnt, float* __restrict__ out, int s)
{
  if (conv_before(uG, s)) return;
  __shared__ __align__(16) unsigned char smem_[65536];
  const int t = threadIdx.x;
  const int w = ((blockIdx.x & 7) << 6) | (blockIdx.x >> 3);  // XCD-chunked (512 = 8*64)
  const int kc = w >> 6, nt = (w & 63) >> 1, bt = w & 1;
  const int n0 = nt * 128, b0 = bt * 128;

  f32x4 acc[4][4];
  #pragma unroll
  for (int r = 0; r < 4; ++r)
    #pragma unroll
    for (int c = 0; c < 4; ++c) { f32x4 z = {0.f,0.f,0.f,0.f}; acc[r][c] = z; }

  gemm_core<32>(WbT, 16384, n0, Et, 16384, b0, kc * 2048, (unsigned short*)smem_, acc, t);

  const int lane = t & 63, wv = t >> 6, l15 = lane & 15, quad = lane >> 4;
  const int wr = wv >> 1, wc = wv & 1;
  float* Pd = P2 + (size_t)kc * 1048576;
  #pragma unroll
  for (int r = 0; r < 4; ++r) {
    const int n = n0 + wr * 64 + r * 16 + quad * 4;
    #pragma unroll
    for (int c = 0; c < 4; ++c) {
      const int b = b0 + wc * 64 + c * 16 + l15;
      #pragma unroll
      for (int j = 0; j < 4; ++j)
        Pd[(size_t)(n + j) * 256 + b] = acc[r][c][j];
    }
  }

  // last-arriver protocol (release/acquire via threadfence); flag parked in smem
  __syncthreads();                       // drains vmcnt: block's stores complete
  if (t == 0) {
    __threadfence();                     // release
    int old = atomicAdd(&cnt[s * 64 + (nt * 2 + bt)], 1);
    *(volatile int*)smem_ = (old == 7) ? 1 : 0;
  }
  __syncthreads();
  const bool last = (*(volatile int*)smem_ != 0);   // block-uniform
  if (!last) return;
  __threadfence();                       // acquire
  __syncthreads();                       // everyone read flag before smem reuse

  // ---- combine tile (nt,bt): 128 n x 128 b ----
  const float dtau = 1.0f / taup[0];
  float* T = (float*)smem_;              // [128][128] f32, XOR col-swizzled (col ^= row&31)
  float d2 = 0.0f;
  {
    const int bl = t & 127, th = t >> 7;
    const int bg = b0 + bl;
    const float inv = 1.0f / csG[s * 256 + bg];
    for (int i = 0; i < 64; ++i) {
      const int nl = i * 2 + th;
      const int n = n0 + nl;
      const float* pp = P2 + (size_t)n * 256 + bg;
      float sum = ((pp[0]       + pp[1048576]) + (pp[2097152] + pp[3145728]))
                + ((pp[4194304] + pp[5242880]) + (pp[6291456] + pp[7340032]));
      float v = sum * inv;
      float old = St[n * 256 + bg];
      float nw = old + dtau * (v - old);
      float d = nw - old;
      d2 += d * d;
      St[n * 256 + bg] = nw;
      T[bl * 128 + (nl ^ (bl & 31))] = nw;
    }
  }
  __syncthreads();
  // coalesced out writes: [b][4096] fp32
  {
    const int nl = t & 127, th = t >> 7;
    #pragma unroll 4
    for (int p = 0; p < 64; ++p) {
      const int bl = p * 2 + th;
      out[(size_t)(b0 + bl) * 4096 + n0 + nl] = T[bl * 128 + (nl ^ (bl & 31))];
    }
  }
  // coalesced Sb writes: [b][4096] bf16
  {
    const int np = (t & 63) * 2, th = t >> 6;
    #pragma unroll 4
    for (int p = 0; p < 32; ++p) {
      const int bl = p * 4 + th;
      const int sw = bl & 31;
      float x0 = T[bl * 128 + (np ^ sw)];
      float x1 = T[bl * 128 + ((np + 1) ^ sw)];
      unsigned u = (unsigned)f2bf(x0) | ((unsigned)f2bf(x1) << 16);
      *(unsigned*)(Sb + (size_t)(b0 + bl) * 4096 + n0 + np) = u;
    }
  }
  // ||delta||^2 reduction -> uG[s]
  #pragma unroll
  for (int o = 32; o > 0; o >>= 1) d2 += __shfl_down(d2, o, 64);
  __syncthreads();
  float* red = (float*)smem_;
  if (lane == 0) red[wv] = d2;
  __syncthreads();
  if (t == 0) atomicAdd(&uG[s], red[0] + red[1] + red[2] + red[3]);
}

// =====================================================================
// ================= OLD PROVEN PATH (ws < 302MB fallback) =============
// =====================================================================
__global__ void __launch_bounds__(256, 2)
k1_gemm1_o(const float* __restrict__ Wg, const float* __restrict__ betap,
           const unsigned short* __restrict__ Sb, unsigned short* __restrict__ Et,
           float* __restrict__ csG, const float* __restrict__ uG, int s)
{
  if (conv_before(uG, s)) return;
  __shared__ __align__(16) unsigned char smem[36864];
  const int t = threadIdx.x;
  const int lane = t & 63;
  const int wv = t >> 6;
  const int quad = lane >> 4;
  const int l15 = lane & 15;
  const float beta = betap[0];

  const int m0 = blockIdx.x * 32;
  unsigned short* As0 = (unsigned short*)(smem);
  unsigned short* As1 = (unsigned short*)(smem + 2048);
  unsigned short* Bs0 = (unsigned short*)(smem + 4096);
  unsigned short* Bs1 = (unsigned short*)(smem + 20480);
  const int ar = t >> 3;
  const int ac = (t & 7) * 4;
  const float* gA = Wg + (size_t)(m0 + ar) * 4096 + ac;
  const int brow = wv * 16 + (lane >> 2);
  const int bcol = (lane & 3) * 8;

  f32x4 acc[2][4];
  #pragma unroll
  for (int r = 0; r < 2; ++r)
    #pragma unroll
    for (int c = 0; c < 4; ++c) { f32x4 z = {0.f,0.f,0.f,0.f}; acc[r][c] = z; }

  float4 arA, arB;
#define LOADA1(itv, dst) { dst = *(const float4*)(gA + (itv) * 32); }
#define WRITEA1(Ad, src) { unsigned short p_[4] __attribute__((aligned(8)));        \
      p_[0]=f2bf((src).x); p_[1]=f2bf((src).y); p_[2]=f2bf((src).z); p_[3]=f2bf((src).w); \
      *(u32x2*)((Ad) + ar * 32 + ac) = *(const u32x2*)p_; }
#define STAGEB1(itv, Bd) { const int k0_ = (itv) * 32 + bcol;                       \
      _Pragma("unroll") for (int j_ = 0; j_ < 4; ++j_)                              \
        gl_lds16(Sb + (size_t)(j_ * 64 + brow) * 4096 + k0_, (Bd) + j_ * 2048 + wv * 512); }

  LOADA1(0, arA); STAGEB1(0, Bs0); WRITEA1(As0, arA); LOADA1(1, arB);
  __syncthreads();

  #pragma unroll 2
  for (int it = 0; it < 128; ++it) {
    unsigned short *Asc, *Bsc, *Asn, *Bsn;
    float4 *arC, *arN;
    if (it & 1) { Asc = As1; Bsc = Bs1; Asn = As0; Bsn = Bs0; arC = &arA; arN = &arB; }
    else        { Asc = As0; Bsc = Bs0; Asn = As1; Bsn = Bs1; arC = &arB; arN = &arA; }
    if (it + 2 < 128) LOADA1(it + 2, (*arN));
    if (it + 1 < 128) { STAGEB1(it + 1, Bsn); WRITEA1(Asn, (*arC)); }
    short8 af[2], bq[4];
    #pragma unroll
    for (int r = 0; r < 2; ++r) af[r] = *(const short8*)(Asc + (16 * r + l15) * 32 + quad * 8);
    #pragma unroll
    for (int c = 0; c < 4; ++c) bq[c] = *(const short8*)(Bsc + (64 * wv + 16 * c + l15) * 32 + quad * 8);
    #pragma unroll
    for (int r = 0; r < 2; ++r)
      #pragma unroll
      for (int c = 0; c < 4; ++c)
        acc[r][c] = __builtin_amdgcn_mfma_f32_16x16x32_bf16(af[r], bq[c], acc[r][c], 0, 0, 0);
    __syncthreads();
  }
#undef LOADA1
#undef WRITEA1
#undef STAGEB1
  #pragma unroll
  for (int c = 0; c < 4; ++c) {
    const int b = 64 * wv + 16 * c + l15;
    float cs = 0.0f;
    #pragma unroll
    for (int r = 0; r < 2; ++r) {
      unsigned short eb[4] __attribute__((aligned(8)));
      #pragma unroll
      for (int j = 0; j < 4; ++j) {
        float e = __expf(beta * acc[r][c][j]);
        cs += e;
        eb[j] = f2bf(e);
      }
      *(u32x2*)(Et + (size_t)b * 16384 + m0 + 16 * r + quad * 4) = *(const u32x2*)eb;
    }
    cs += __shfl_xor(cs, 16, 64);
    cs += __shfl_xor(cs, 32, 64);
    if (quad == 0) atomicAdd(&csG[s * 256 + b], cs);
  }
}

__global__ void __launch_bounds__(256, 2)
k2_gemm2_o(const float* __restrict__ Wg, const float* __restrict__ taup,
           const unsigned short* __restrict__ Et, float* __restrict__ P2,
           float* __restrict__ St, unsigned short* __restrict__ Sb,
           const float* __restrict__ csG, float* __restrict__ uG,
           int* __restrict__ cnt, float* __restrict__ out, int s)
{
  if (conv_before(uG, s)) return;
  __shared__ __align__(16) unsigned char smem[37888];
  __shared__ int lastF;
  const int t = threadIdx.x;
  const int lane = t & 63;
  const int wv = t >> 6;
  const int quad = lane >> 4;
  const int l15 = lane & 15;
  const int rt = blockIdx.x & 127;
  const int kc = blockIdx.x >> 7;
  const int n0 = rt * 32;
  const int mb = kc * 4096;

  unsigned short* As0 = (unsigned short*)(smem);
  unsigned short* As1 = (unsigned short*)(smem + 2560);
  unsigned short* Bs0 = (unsigned short*)(smem + 5120);
  unsigned short* Bs1 = (unsigned short*)(smem + 21504);
  const int mp = (t >> 4) * 2;
  const int ng = (t & 15) * 2;
  const int brow = wv * 16 + (lane >> 2);
  const int bcol = (lane & 3) * 8;

  f32x4 acc[2][4];
  #pragma unroll
  for (int r = 0; r < 2; ++r)
    #pragma unroll
    for (int c = 0; c < 4; ++c) { f32x4 z = {0.f,0.f,0.f,0.f}; acc[r][c] = z; }

  float2 aA0, aA1, aB0, aB1;
#define LOADA2(itv, d0, d1) { const float* g_ = Wg + (size_t)(mb + (itv) * 32 + mp) * 4096 + n0 + ng; \
      d0 = *(const float2*)g_; d1 = *(const float2*)(g_ + 4096); }
#define WRITEA2(Ad, d0, d1) {                                                       \
      unsigned x0_ = (unsigned)f2bf((d0).x) | ((unsigned)f2bf((d1).x) << 16);       \
      unsigned x1_ = (unsigned)f2bf((d0).y) | ((unsigned)f2bf((d1).y) << 16);       \
      *(unsigned*)((Ad) + ng * 40 + mp) = x0_;                                      \
      *(unsigned*)((Ad) + (ng + 1) * 40 + mp) = x1_; }
#define STAGEB2(itv, Bd) { const int k0_ = mb + (itv) * 32 + bcol;                  \
      _Pragma("unroll") for (int j_ = 0; j_ < 4; ++j_)                              \
        gl_lds16(Et + (size_t)(j_ * 64 + brow) * 16384 + k0_, (Bd) + j_ * 2048 + wv * 512); }

  LOADA2(0, aA0, aA1); STAGEB2(0, Bs0); WRITEA2(As0, aA0, aA1); LOADA2(1, aB0, aB1);
  __syncthreads();

  #pragma unroll 2
  for (int it = 0; it < 128; ++it) {
    unsigned short *Asc, *Bsc, *Asn, *Bsn;
    float2 *c0, *c1, *n0p, *n1p;
    if (it & 1) { Asc = As1; Bsc = Bs1; Asn = As0; Bsn = Bs0; c0 = &aA0; c1 = &aA1; n0p = &aB0; n1p = &aB1; }
    else        { Asc = As0; Bsc = Bs0; Asn = As1; Bsn = Bs1; c0 = &aB0; c1 = &aB1; n0p = &aA0; n1p = &aA1; }
    if (it + 2 < 128) LOADA2(it + 2, (*n0p), (*n1p));
    if (it + 1 < 128) { STAGEB2(it + 1, Bsn); WRITEA2(Asn, (*c0), (*c1)); }
    short8 af[2], bq[4];
    #pragma unroll
    for (int r = 0; r < 2; ++r) af[r] = *(const short8*)(Asc + (16 * r + l15) * 40 + quad * 8);
    #pragma unroll
    for (int c = 0; c < 4; ++c) bq[c] = *(const short8*)(Bsc + (64 * wv + 16 * c + l15) * 32 + quad * 8);
    #pragma unroll
    for (int r = 0; r < 2; ++r)
      #pragma unroll
      for (int c = 0; c < 4; ++c)
        acc[r][c] = __builtin_amdgcn_mfma_f32_16x16x32_bf16(af[r], bq[c], acc[r][c], 0, 0, 0);
    __syncthreads();
  }
#undef LOADA2
#undef WRITEA2
#undef STAGEB2
  float* Pd = P2 + (size_t)kc * 1048576;
  #pragma unroll
  for (int r = 0; r < 2; ++r)
    #pragma unroll
    for (int c = 0; c < 4; ++c) {
      const int b = 64 * wv + 16 * c + l15;
      #pragma unroll
      for (int j = 0; j < 4; ++j)
        Pd[(size_t)(n0 + 16 * r + quad * 4 + j) * 256 + b] = acc[r][c][j];
    }

  __syncthreads();
  if (t == 0) {
    __threadfence();
    int old = atomicAdd(&cnt[s * 128 + rt], 1);
    lastF = (old == 3);
  }
  __syncthreads();
  if (!lastF) return;
  __threadfence();

  const float dtau = 1.0f / taup[0];
  const float inv = 1.0f / csG[s * 256 + t];
  float* T = (float*)smem;
  float d2 = 0.0f;
  for (int i = 0; i < 32; ++i) {
    const int n = n0 + i;
    const float* pp = P2 + (size_t)n * 256 + t;
    float sum = pp[0] + pp[1048576] + pp[2097152] + pp[3145728];
    float v = sum * inv;
    float old = St[n * 256 + t];
    float nw = old + dtau * (v - old);
    float d = nw - old;
    d2 += d * d;
    St[n * 256 + t] = nw;
    T[t * 33 + i] = nw;
  }
  __syncthreads();
  #pragma unroll 4
  for (int p = 0; p < 32; ++p) {
    const int b = p * 8 + (t >> 5);
    const int nl = t & 31;
    out[(size_t)b * 4096 + n0 + nl] = T[b * 33 + nl];
  }
  #pragma unroll 4
  for (int p = 0; p < 16; ++p) {
    const int b = p * 16 + (t >> 4);
    const int np = (t & 15) * 2;
    unsigned u = (unsigned)f2bf(T[b * 33 + np]) | ((unsigned)f2bf(T[b * 33 + np + 1]) << 16);
    *(unsigned*)(Sb + (size_t)b * 4096 + n0 + np) = u;
  }
  #pragma unroll
  for (int o = 32; o > 0; o >>= 1) d2 += __shfl_down(d2, o, 64);
  __syncthreads();
  float* red = (float*)smem;
  if (lane == 0) red[wv] = d2;
  __syncthreads();
  if (t == 0) atomicAdd(&uG[s], red[0] + red[1] + red[2] + red[3]);
}

extern "C" void kernel_launch(void* const* d_in, const int* in_sizes, int n_in,
                              void* d_out, int out_size, void* d_ws, size_t ws_size,
                              hipStream_t stream) {
  const float* inp   = (const float*)d_in[0];   // [256,4096,1]
  const float* W     = (const float*)d_in[1];   // [16384,4096]
  const float* betap = (const float*)d_in[2];
  const float* taup  = (const float*)d_in[3];
  float* out = (float*)d_out;
  char* ws = (char*)d_ws;

  if (ws_size >= (size_t)WS_END) {
    // -------- new path: bf16 W copies + 128x128 direct-gl_lds GEMMs --------
    unsigned short* Et = (unsigned short*)(ws + WS_ET);
    float*          P2 = (float*)(ws + WS_P2);
    float*          St = (float*)(ws + WS_ST);
    unsigned short* Sb = (unsigned short*)(ws + WS_SB);
    float*          cs = (float*)(ws + WS_CS);
    float*          uG = (float*)(ws + WS_UG);
    int*            cn = (int*)(ws + WS_CNT);
    unsigned short* Wb = (unsigned short*)(ws + WS_WB);
    unsigned short* Wt = (unsigned short*)(ws + WS_WBT);

    hipLaunchKernelGGL(k0_setup, dim3(512), dim3(256), 0, stream, inp, St, Sb, cs, uG, cn);
    hipLaunchKernelGGL(k0w_conv, dim3(4096), dim3(256), 0, stream, W, Wb, Wt);
    for (int s = 0; s < 50; ++s) {
      hipLaunchKernelGGL(k1_gemm1, dim3(256), dim3(256), 0, stream, Wb, betap, Sb, Et, cs, uG, s);
      hipLaunchKernelGGL(k2_gemm2, dim3(512), dim3(256), 0, stream, Wt, taup, Et, P2, St, Sb, cs, uG, cn, out, s);
    }
  } else if (ws_size >= (size_t)WO_END) {
    // -------- old proven fallback path --------
    unsigned short* Et = (unsigned short*)(ws + WO_ET);
    float*          P2 = (float*)(ws + WO_P2);
    float*          St = (float*)(ws + WO_ST);
    unsigned short* Sb = (unsigned short*)(ws + WO_SB);
    float*          cs = (float*)(ws + WO_CS);
    float*          uG = (float*)(ws + WO_UG);
    int*            cn = (int*)(ws + WO_CNT);

    hipLaunchKernelGGL(k0_setup, dim3(512), dim3(256), 0, stream, inp, St, Sb, cs, uG, cn);
    for (int s = 0; s < 50; ++s) {
      hipLaunchKernelGGL(k1_gemm1_o, dim3(512), dim3(256), 0, stream, W, betap, Sb, Et, cs, uG, s);
      hipLaunchKernelGGL(k2_gemm2_o, dim3(512), dim3(256), 0, stream, W, taup, Et, P2, St, Sb, cs, uG, cn, out, s);
    }
  } else {
    hipLaunchKernelGGL(sentinel_kernel, dim3(1), dim3(1), 0, stream, out, 1.0e6f);
  }
}